// Round 14
// baseline (232.385 us; speedup 1.0000x reference)
//
#include <hip/hip_runtime.h>
#include <hip/hip_bf16.h>

typedef __attribute__((ext_vector_type(8))) short short8;
typedef __attribute__((ext_vector_type(4))) float f32x4;

// bf16 truncation (round-toward-zero). Safe: s = ||z3||^2 cancels exactly in
// out = s*d / max(s*sqrt(n1*n2), eps); only d,n1,n2 (pure f32) reach out.
__device__ __forceinline__ unsigned int bfhi(float f) {
    return __builtin_bit_cast(unsigned int, f);
}
__device__ __forceinline__ unsigned int pack2(float lo, float hi) {
    return (bfhi(lo) >> 16) | (bfhi(hi) & 0xffff0000u);
}

// ============================ DIAGNOSTIC ABLATION ============================
// Q-path of the R9 kernel, split into REP'd phases. MODE:
//  0: rep{stage}            1: stage once; rep{GEMM1}
//  2: rep{stage+GEMM1}      3: stage+GEMM1 once; rep{GEMM2+GEMM3}
template<int MODE, int REPN>
__global__ __launch_bounds__(512, 4) void abl(
    const float* __restrict__ X,
    const unsigned short* __restrict__ wsb,
    const float* __restrict__ b1,
    const float* __restrict__ b2,
    const float* __restrict__ b3,
    float* __restrict__ scratch)
{
    __shared__ __align__(16) char xq[16 * 1536];
    __shared__ __align__(16) unsigned short z1[16][136];
    __shared__ __align__(16) unsigned short z2[16][72];

    const int tid  = threadIdx.x;
    const int wid  = tid >> 6;
    const int lane = tid & 63;
    const int l15  = lane & 15;
    const int l4   = lane >> 4;
    const int row0 = (int)blockIdx.x * 16;
    float keep = 0.f;

    auto STAGE = [&]() {
        float4 q[6];
        int qr[3], qc[3];
#pragma unroll
        for (int j = 0; j < 3; ++j) {
            int ci = tid + 512 * j;
            int r  = ci / 96;
            int cc = ci - r * 96;
            qr[j] = r; qc[j] = cc;
            const float* p = X + (size_t)(row0 + r) * 2304 + cc * 8;
            q[2 * j]     = *(const float4*)(p);
            q[2 * j + 1] = *(const float4*)(p + 4);
        }
#pragma unroll
        for (int j = 0; j < 3; ++j) {
            uint4 u;
            u.x = pack2(q[2 * j].x,     q[2 * j].y);
            u.y = pack2(q[2 * j].z,     q[2 * j].w);
            u.z = pack2(q[2 * j + 1].x, q[2 * j + 1].y);
            u.w = pack2(q[2 * j + 1].z, q[2 * j + 1].w);
            int byteoff = (qr[j] * 1536 + qc[j] * 16) ^ ((qr[j] & 7) << 4);
            *(uint4*)(xq + byteoff) = u;
        }
    };
    auto GEMM1 = [&]() {
        f32x4 acc = {0.f, 0.f, 0.f, 0.f};
        const unsigned short* bp = wsb + (size_t)(16 * wid + l15) * 768 + l4 * 8;
        const int abase = l15 * 1536;
        const int aswz  = (l15 & 7) << 4;
        short8 bcur = *(const short8*)(bp);
#pragma unroll
        for (int k0 = 0; k0 < 768; k0 += 32) {
            short8 bnext = (k0 < 736) ? *(const short8*)(bp + k0 + 32) : bcur;
            short8 a = *(const short8*)(xq + ((abase + (k0 + l4 * 8) * 2) ^ aswz));
            acc = __builtin_amdgcn_mfma_f32_16x16x32_bf16(a, bcur, acc, 0, 0, 0);
            bcur = bnext;
        }
        float bv = b1[16 * wid + l15];
#pragma unroll
        for (int r = 0; r < 4; ++r) {
            float v = fmaxf(acc[r] + bv, 0.f);
            z1[4 * l4 + r][16 * wid + l15] = (unsigned short)(bfhi(v) >> 16);
            keep += v;
        }
    };
    auto TAIL = [&]() {
        if (wid < 4) {
            f32x4 acc = {0.f, 0.f, 0.f, 0.f};
            const unsigned short* bp = wsb + 98304 + (16 * wid + l15) * 128 + l4 * 8;
#pragma unroll
            for (int ks = 0; ks < 4; ++ks) {
                short8 a = *(const short8*)&z1[l15][ks * 32 + l4 * 8];
                short8 b = *(const short8*)(bp + ks * 32);
                acc = __builtin_amdgcn_mfma_f32_16x16x32_bf16(a, b, acc, 0, 0, 0);
            }
            float bv = b2[16 * wid + l15];
#pragma unroll
            for (int r = 0; r < 4; ++r) {
                float v = fmaxf(acc[r] + bv, 0.f);
                z2[4 * l4 + r][16 * wid + l15] = (unsigned short)(bfhi(v) >> 16);
            }
        }
        __syncthreads();
        if (wid < 2) {
            f32x4 acc = {0.f, 0.f, 0.f, 0.f};
            const unsigned short* bp = wsb + 106496 + (16 * wid + l15) * 64 + l4 * 8;
#pragma unroll
            for (int ks = 0; ks < 2; ++ks) {
                short8 a = *(const short8*)&z2[l15][ks * 32 + l4 * 8];
                short8 b = *(const short8*)(bp + ks * 32);
                acc = __builtin_amdgcn_mfma_f32_16x16x32_bf16(a, b, acc, 0, 0, 0);
            }
            float bv = b3[16 * wid + l15];
#pragma unroll
            for (int r = 0; r < 4; ++r) {
                float v = fmaxf(acc[r] + bv, 0.f);
                keep += v * v;
            }
        }
    };

    if (MODE == 1 || MODE == 3) { STAGE(); __syncthreads(); }
    if (MODE == 3) { GEMM1(); __syncthreads(); }

    for (int rep = 0; rep < REPN; ++rep) {
        asm volatile("" ::: "memory");
        if (MODE == 0 || MODE == 2) {
            STAGE();
            __syncthreads();
            keep += *(const float*)(xq + ((tid * 16) & (16 * 1536 - 16)));
            __syncthreads();   // WAR: next rep overwrites xq
        }
        if (MODE == 1 || MODE == 2) {
            GEMM1();
            if (MODE == 2) __syncthreads();
        }
        if (MODE == 3) {
            TAIL();
            __syncthreads();   // WAR on z2
        }
    }
#pragma unroll
    for (int m = 1; m < 64; m <<= 1) keep += __shfl_xor(keep, m);
    if (lane == 0) scratch[blockIdx.x * 8 + wid] = keep;
}

// ============================ REAL PIPELINE (R9, passing) ===================
__global__ __launch_bounds__(256) void cvt_weights(
    const float* __restrict__ W1, const float* __restrict__ W2,
    const float* __restrict__ W3, unsigned short* __restrict__ wsb)
{
    int i4 = (blockIdx.x * 256 + threadIdx.x) * 4;
    const float* src;
    int off;
    if (i4 < 98304)       { src = W1; off = 0; }
    else if (i4 < 106496) { src = W2; off = 98304; }
    else                  { src = W3; off = 106496; }
    float4 v = *(const float4*)(src + (i4 - off));
    uint2 u;
    u.x = pack2(v.x, v.y);
    u.y = pack2(v.z, v.w);
    *(uint2*)&wsb[i4] = u;
}

__global__ __launch_bounds__(512, 6) void pq_kernel(
    const float* __restrict__ X,
    const unsigned short* __restrict__ wsb,
    const float* __restrict__ b1,
    const float* __restrict__ b2,
    const float* __restrict__ b3,
    float* __restrict__ wsf)
{
    __shared__ __align__(16) char xq[16 * 1536];
    __shared__ __align__(16) unsigned short z1[16][136];
    __shared__ __align__(16) unsigned short z2[16][72];
    __shared__ float sred[2][16];

    const int tid  = threadIdx.x;
    const int wid  = tid >> 6;
    const int lane = tid & 63;
    const int l15  = lane & 15;
    const int l4   = lane >> 4;

    if (blockIdx.x >= 256) {
        const int row = (int)(blockIdx.x - 256) * 8 + wid;
        const float* base = X + (size_t)row * 2304;
        float4 p1[3], p2[3];
#pragma unroll
        for (int m = 0; m < 3; ++m) p1[m] = *(const float4*)(base + 768 + (lane + 64 * m) * 4);
#pragma unroll
        for (int m = 0; m < 3; ++m) p2[m] = *(const float4*)(base + 1536 + (lane + 64 * m) * 4);
        float dd = 0.f, aa = 0.f, bb = 0.f;
#pragma unroll
        for (int m = 0; m < 3; ++m) {
            float4 x = p1[m], y = p2[m];
            dd += x.x * y.x + x.y * y.y + x.z * y.z + x.w * y.w;
            aa += x.x * x.x + x.y * x.y + x.z * x.z + x.w * x.w;
            bb += y.x * y.x + y.y * y.y + y.z * y.z + y.w * y.w;
        }
#pragma unroll
        for (int m = 1; m < 64; m <<= 1) {
            dd += __shfl_xor(dd, m);
            aa += __shfl_xor(aa, m);
            bb += __shfl_xor(bb, m);
        }
        if (lane == 0) {
            wsf[row]        = dd;
            wsf[4096 + row] = aa;
            wsf[8192 + row] = bb;
        }
        return;
    }

    const int row0 = (int)blockIdx.x * 16;
    {
        float4 q[6];
        int qr[3], qc[3];
#pragma unroll
        for (int j = 0; j < 3; ++j) {
            int ci = tid + 512 * j;
            int r  = ci / 96;
            int cc = ci - r * 96;
            qr[j] = r; qc[j] = cc;
            const float* p = X + (size_t)(row0 + r) * 2304 + cc * 8;
            q[2 * j]     = *(const float4*)(p);
            q[2 * j + 1] = *(const float4*)(p + 4);
        }
#pragma unroll
        for (int j = 0; j < 3; ++j) {
            uint4 u;
            u.x = pack2(q[2 * j].x,     q[2 * j].y);
            u.y = pack2(q[2 * j].z,     q[2 * j].w);
            u.z = pack2(q[2 * j + 1].x, q[2 * j + 1].y);
            u.w = pack2(q[2 * j + 1].z, q[2 * j + 1].w);
            int byteoff = (qr[j] * 1536 + qc[j] * 16) ^ ((qr[j] & 7) << 4);
            *(uint4*)(xq + byteoff) = u;
        }
    }
    __syncthreads();
    {
        f32x4 acc = {0.f, 0.f, 0.f, 0.f};
        const unsigned short* bp = wsb + (size_t)(16 * wid + l15) * 768 + l4 * 8;
        const int abase = l15 * 1536;
        const int aswz  = (l15 & 7) << 4;
        short8 bcur = *(const short8*)(bp);
#pragma unroll
        for (int k0 = 0; k0 < 768; k0 += 32) {
            short8 bnext = (k0 < 736) ? *(const short8*)(bp + k0 + 32) : bcur;
            short8 a = *(const short8*)(xq + ((abase + (k0 + l4 * 8) * 2) ^ aswz));
            acc = __builtin_amdgcn_mfma_f32_16x16x32_bf16(a, bcur, acc, 0, 0, 0);
            bcur = bnext;
        }
        float bv = b1[16 * wid + l15];
#pragma unroll
        for (int r = 0; r < 4; ++r) {
            float v = fmaxf(acc[r] + bv, 0.f);
            z1[4 * l4 + r][16 * wid + l15] = (unsigned short)(bfhi(v) >> 16);
        }
    }
    __syncthreads();
    if (wid < 4) {
        f32x4 acc = {0.f, 0.f, 0.f, 0.f};
        const unsigned short* bp = wsb + 98304 + (16 * wid + l15) * 128 + l4 * 8;
#pragma unroll
        for (int ks = 0; ks < 4; ++ks) {
            short8 a = *(const short8*)&z1[l15][ks * 32 + l4 * 8];
            short8 b = *(const short8*)(bp + ks * 32);
            acc = __builtin_amdgcn_mfma_f32_16x16x32_bf16(a, b, acc, 0, 0, 0);
        }
        float bv = b2[16 * wid + l15];
#pragma unroll
        for (int r = 0; r < 4; ++r) {
            float v = fmaxf(acc[r] + bv, 0.f);
            z2[4 * l4 + r][16 * wid + l15] = (unsigned short)(bfhi(v) >> 16);
        }
    }
    __syncthreads();
    if (wid < 2) {
        f32x4 acc = {0.f, 0.f, 0.f, 0.f};
        const unsigned short* bp = wsb + 106496 + (16 * wid + l15) * 64 + l4 * 8;
#pragma unroll
        for (int ks = 0; ks < 2; ++ks) {
            short8 a = *(const short8*)&z2[l15][ks * 32 + l4 * 8];
            short8 b = *(const short8*)(bp + ks * 32);
            acc = __builtin_amdgcn_mfma_f32_16x16x32_bf16(a, b, acc, 0, 0, 0);
        }
        float bv = b3[16 * wid + l15];
        float sv[4];
#pragma unroll
        for (int r = 0; r < 4; ++r) {
            float v = fmaxf(acc[r] + bv, 0.f);
            sv[r] = v * v;
        }
#pragma unroll
        for (int m = 1; m < 16; m <<= 1)
#pragma unroll
            for (int r = 0; r < 4; ++r) sv[r] += __shfl_xor(sv[r], m);
        if (l15 == 0)
#pragma unroll
            for (int r = 0; r < 4; ++r) sred[wid][4 * l4 + r] = sv[r];
    }
    __syncthreads();
    if (tid < 16) wsf[12288 + row0 + tid] = sred[0][tid] + sred[1][tid];
}

__global__ __launch_bounds__(512) void combine(
    const float* __restrict__ wsf, float* __restrict__ out)
{
    int i = blockIdx.x * 512 + threadIdx.x;
    float d  = wsf[i];
    float n1 = wsf[4096 + i];
    float n2 = wsf[8192 + i];
    float s  = wsf[12288 + i];
    out[i] = (s * d) / fmaxf(s * sqrtf(n1 * n2), 1e-8f);
}

extern "C" void kernel_launch(void* const* d_in, const int* in_sizes, int n_in,
                              void* d_out, int out_size, void* d_ws, size_t ws_size,
                              hipStream_t stream)
{
    (void)in_sizes; (void)n_in; (void)out_size; (void)ws_size;
    const float* X  = (const float*)d_in[0];
    const float* W1 = (const float*)d_in[1];
    const float* b1 = (const float*)d_in[2];
    const float* W2 = (const float*)d_in[3];
    const float* b2 = (const float*)d_in[4];
    const float* W3 = (const float*)d_in[5];
    const float* b3 = (const float*)d_in[6];

    float* wsf          = (float*)d_ws;                   // d, n1, n2, s (4x4096)
    unsigned short* wsb = (unsigned short*)(wsf + 16384); // bf16 weights
    float* scratch      = wsf + 71680;                    // ablation keep-alive

    cvt_weights<<<dim3(106), dim3(256), 0, stream>>>(W1, W2, W3, wsb);

    // -------- DIAGNOSTIC ablations (write only to scratch) --------
    abl<0, 32><<<dim3(256), dim3(512), 0, stream>>>(X, wsb, b1, b2, b3, scratch);
    abl<1, 16><<<dim3(256), dim3(512), 0, stream>>>(X, wsb, b1, b2, b3, scratch);
    abl<2, 12><<<dim3(256), dim3(512), 0, stream>>>(X, wsb, b1, b2, b3, scratch);
    abl<3, 32><<<dim3(256), dim3(512), 0, stream>>>(X, wsb, b1, b2, b3, scratch);

    // -------- real pipeline (R9, passing) --------
    pq_kernel<<<dim3(768), dim3(512), 0, stream>>>(X, wsb, b1, b2, b3, wsf);
    combine<<<dim3(8), dim3(512), 0, stream>>>(wsf, (float*)d_out);
}

// Round 15
// 24.065 us; speedup vs baseline: 9.6566x; 9.6566x over previous
//
#include <hip/hip_runtime.h>
#include <hip/hip_bf16.h>

typedef __attribute__((ext_vector_type(8))) short short8;
typedef __attribute__((ext_vector_type(4))) float f32x4;

// bf16 truncation (round-toward-zero). Safe: s = ||z3||^2 cancels exactly in
// out = s*d / max(s*sqrt(n1*n2), eps); only d,n1,n2 (pure f32) reach out.
__device__ __forceinline__ unsigned int bfhi(float f) {
    return __builtin_bit_cast(unsigned int, f);
}
__device__ __forceinline__ unsigned int pack2(float lo, float hi) {
    return (bfhi(lo) >> 16) | (bfhi(hi) & 0xffff0000u);
}
__device__ __forceinline__ short8 pack_bf8(float4 a, float4 b) {
    uint4 u;
    u.x = pack2(a.x, a.y);
    u.y = pack2(a.z, a.w);
    u.z = pack2(b.x, b.y);
    u.w = pack2(b.z, b.w);
    return __builtin_bit_cast(short8, u);
}

// ONE kernel. 256 blocks x 512 threads (8 waves), 16 rows/block, 1 block/CU.
// Phase A: ALL X loads issued up-front (Xq 6 float4/thread; Xp 12 float4/lane,
//          half-wave = row); Xq -> LDS bf16 XOR-swizzled; Xp -> d,n1,n2 (LDS).
// Phase B: GEMM1 (M=16,N=128,K=768), W1 f32 DIRECT with DEPTH-12 register
//          rotation: 24 independent loads in flight (the P-path's memory
//          shape), ~250cy slack per load vs L2/L3 latency. In-register pack.
// Phase C: GEMM2 (waves 0-3), GEMM3 + s=||z3||^2 (waves 0-1), W2/W3 f32
//          packed in-register (loads fully unrolled -> all in flight).
// Phase D: tid<16 writes out = s*d / max(s*sqrt(n1*n2), eps).
__global__ __launch_bounds__(512, 2) void fused_all(
    const float* __restrict__ X,
    const float* __restrict__ W1, const float* __restrict__ b1,
    const float* __restrict__ W2, const float* __restrict__ b2,
    const float* __restrict__ W3, const float* __restrict__ b3,
    float* __restrict__ out)
{
    __shared__ __align__(16) char xq[16 * 1536];          // 16x768 bf16, XOR-swizzled
    __shared__ __align__(16) unsigned short z1[16][136];
    __shared__ __align__(16) unsigned short z2[16][72];
    __shared__ float sred[2][16];
    __shared__ float d_l[16], n1_l[16], n2_l[16];

    const int tid  = threadIdx.x;
    const int wid  = tid >> 6;
    const int lane = tid & 63;
    const int l15  = lane & 15;
    const int l4   = lane >> 4;
    const int row0 = (int)blockIdx.x * 16;

    // ---------------- Phase A: all X loads up-front ----------------
    {
        float4 q[6];
        int qr[3], qc[3];
#pragma unroll
        for (int j = 0; j < 3; ++j) {
            int ci = tid + 512 * j;
            int r  = ci / 96;
            int cc = ci - r * 96;
            qr[j] = r; qc[j] = cc;
            const float* p = X + (size_t)(row0 + r) * 2304 + cc * 8;
            q[2 * j]     = *(const float4*)(p);
            q[2 * j + 1] = *(const float4*)(p + 4);
        }
        const int hl = lane >> 5, ln = lane & 31;
        const int prow = 2 * wid + hl;
        const float* pb = X + (size_t)(row0 + prow) * 2304;
        float4 p1[6], p2[6];
#pragma unroll
        for (int m = 0; m < 6; ++m) p1[m] = *(const float4*)(pb + 768 + (ln + 32 * m) * 4);
#pragma unroll
        for (int m = 0; m < 6; ++m) p2[m] = *(const float4*)(pb + 1536 + (ln + 32 * m) * 4);

#pragma unroll
        for (int j = 0; j < 3; ++j) {
            uint4 u;
            u.x = pack2(q[2 * j].x,     q[2 * j].y);
            u.y = pack2(q[2 * j].z,     q[2 * j].w);
            u.z = pack2(q[2 * j + 1].x, q[2 * j + 1].y);
            u.w = pack2(q[2 * j + 1].z, q[2 * j + 1].w);
            int byteoff = (qr[j] * 1536 + qc[j] * 16) ^ ((qr[j] & 7) << 4);
            *(uint4*)(xq + byteoff) = u;
        }
        float dd = 0.f, aa = 0.f, bb = 0.f;
#pragma unroll
        for (int m = 0; m < 6; ++m) {
            float4 x = p1[m], y = p2[m];
            dd += x.x * y.x + x.y * y.y + x.z * y.z + x.w * y.w;
            aa += x.x * x.x + x.y * x.y + x.z * x.z + x.w * x.w;
            bb += y.x * y.x + y.y * y.y + y.z * y.z + y.w * y.w;
        }
#pragma unroll
        for (int m = 1; m < 32; m <<= 1) {
            dd += __shfl_xor(dd, m);
            aa += __shfl_xor(aa, m);
            bb += __shfl_xor(bb, m);
        }
        if (ln == 0) {
            d_l[prow]  = dd;
            n1_l[prow] = aa;
            n2_l[prow] = bb;
        }
    }
    __syncthreads();

    // ---------------- Phase B: GEMM1, depth-12 B rotation ----------------
    {
        f32x4 acc = {0.f, 0.f, 0.f, 0.f};
        const float* bp = W1 + (size_t)(16 * wid + l15) * 768 + l4 * 8;
        const int abase = l15 * 1536;
        const int aswz  = (l15 & 7) << 4;
        float4 wa[12], wb[12];
#pragma unroll
        for (int i = 0; i < 12; ++i) {
            wa[i] = *(const float4*)(bp + i * 32);
            wb[i] = *(const float4*)(bp + i * 32 + 4);
        }
#pragma unroll
        for (int it = 0; it < 24; ++it) {
            const int slot = it % 12;
            short8 b = pack_bf8(wa[slot], wb[slot]);
            short8 a = *(const short8*)(xq + ((abase + (it * 32 + l4 * 8) * 2) ^ aswz));
            acc = __builtin_amdgcn_mfma_f32_16x16x32_bf16(a, b, acc, 0, 0, 0);
            if (it < 12) {
                wa[slot] = *(const float4*)(bp + (it + 12) * 32);
                wb[slot] = *(const float4*)(bp + (it + 12) * 32 + 4);
            }
        }
        float bv = b1[16 * wid + l15];
#pragma unroll
        for (int r = 0; r < 4; ++r) {
            float v = fmaxf(acc[r] + bv, 0.f);
            z1[4 * l4 + r][16 * wid + l15] = (unsigned short)(bfhi(v) >> 16);
        }
    }
    __syncthreads();

    // ---------------- Phase C1: GEMM2 (waves 0-3) ----------------
    if (wid < 4) {
        f32x4 acc = {0.f, 0.f, 0.f, 0.f};
        const float* bp = W2 + (size_t)(16 * wid + l15) * 128 + l4 * 8;
#pragma unroll
        for (int ks = 0; ks < 4; ++ks) {
            short8 b = pack_bf8(*(const float4*)(bp + ks * 32),
                                *(const float4*)(bp + ks * 32 + 4));
            short8 a = *(const short8*)&z1[l15][ks * 32 + l4 * 8];
            acc = __builtin_amdgcn_mfma_f32_16x16x32_bf16(a, b, acc, 0, 0, 0);
        }
        float bv = b2[16 * wid + l15];
#pragma unroll
        for (int r = 0; r < 4; ++r) {
            float v = fmaxf(acc[r] + bv, 0.f);
            z2[4 * l4 + r][16 * wid + l15] = (unsigned short)(bfhi(v) >> 16);
        }
    }
    __syncthreads();

    // ---------------- Phase C2: GEMM3 + s = ||z3||^2 (waves 0-1) ----------------
    if (wid < 2) {
        f32x4 acc = {0.f, 0.f, 0.f, 0.f};
        const float* bp = W3 + (size_t)(16 * wid + l15) * 64 + l4 * 8;
#pragma unroll
        for (int ks = 0; ks < 2; ++ks) {
            short8 b = pack_bf8(*(const float4*)(bp + ks * 32),
                                *(const float4*)(bp + ks * 32 + 4));
            short8 a = *(const short8*)&z2[l15][ks * 32 + l4 * 8];
            acc = __builtin_amdgcn_mfma_f32_16x16x32_bf16(a, b, acc, 0, 0, 0);
        }
        float bv = b3[16 * wid + l15];
        float sv[4];
#pragma unroll
        for (int r = 0; r < 4; ++r) {
            float v = fmaxf(acc[r] + bv, 0.f);
            sv[r] = v * v;
        }
#pragma unroll
        for (int m = 1; m < 16; m <<= 1)
#pragma unroll
            for (int r = 0; r < 4; ++r) sv[r] += __shfl_xor(sv[r], m);
        if (l15 == 0)
#pragma unroll
            for (int r = 0; r < 4; ++r) sred[wid][4 * l4 + r] = sv[r];
    }
    __syncthreads();

    // ---------------- Phase D: combine ----------------
    if (tid < 16) {
        float s   = sred[0][tid] + sred[1][tid];
        float den = fmaxf(s * sqrtf(n1_l[tid] * n2_l[tid]), 1e-8f);
        out[row0 + tid] = (s * d_l[tid]) / den;
    }
}

extern "C" void kernel_launch(void* const* d_in, const int* in_sizes, int n_in,
                              void* d_out, int out_size, void* d_ws, size_t ws_size,
                              hipStream_t stream)
{
    (void)in_sizes; (void)n_in; (void)out_size; (void)d_ws; (void)ws_size;
    const float* X  = (const float*)d_in[0];
    const float* W1 = (const float*)d_in[1];
    const float* b1 = (const float*)d_in[2];
    const float* W2 = (const float*)d_in[3];
    const float* b2 = (const float*)d_in[4];
    const float* W3 = (const float*)d_in[5];
    const float* b3 = (const float*)d_in[6];

    fused_all<<<dim3(256), dim3(512), 0, stream>>>(X, W1, b1, W2, b2, W3, b3,
                                                   (float*)d_out);
}

// Round 16
// 22.954 us; speedup vs baseline: 10.1240x; 1.0484x over previous
//
#include <hip/hip_runtime.h>
#include <hip/hip_bf16.h>

typedef __attribute__((ext_vector_type(8))) short short8;
typedef __attribute__((ext_vector_type(4))) float f32x4;

// bf16 truncation (round-toward-zero). Safe: s = ||z3||^2 cancels exactly in
// out = s*d / max(s*sqrt(n1*n2), eps); only d,n1,n2 (pure f32) reach out.
__device__ __forceinline__ unsigned int bfhi(float f) {
    return __builtin_bit_cast(unsigned int, f);
}
__device__ __forceinline__ unsigned int pack2(float lo, float hi) {
    return (bfhi(lo) >> 16) | (bfhi(hi) & 0xffff0000u);
}

// K0: convert W1/W2/W3 f32 -> bf16 into ws (vectorized x4).
// ushort layout: W1b @ 0 (98304), W2b @ 98304 (8192), W3b @ 106496 (2048).
__global__ __launch_bounds__(256) void cvt_weights(
    const float* __restrict__ W1, const float* __restrict__ W2,
    const float* __restrict__ W3, unsigned short* __restrict__ wsb)
{
    int i4 = (blockIdx.x * 256 + threadIdx.x) * 4;
    const float* src;
    int off;
    if (i4 < 98304)       { src = W1; off = 0; }
    else if (i4 < 106496) { src = W2; off = 98304; }
    else                  { src = W3; off = 106496; }
    float4 v = *(const float4*)(src + (i4 - off));
    uint2 u;
    u.x = pack2(v.x, v.y);
    u.y = pack2(v.z, v.w);
    *(uint2*)&wsb[i4] = u;
}

// K1: R9's phases re-cut into 4-wave blocks for block-level phase overlap.
// 768 blocks x 256 threads; Q-block LDS ~31KB -> 5 blocks/CU co-resident
// (20 waves/CU vs R9's 8): while one block barriers, others stream/MFMA.
//   bid 0..255  (Q): 16 real rows. Stage Xq -> LDS bf16 XOR-swizzled (6
//     chunks/thread, all 12 float4 in flight); GEMM1 M=16,N=128,K=768 with
//     wave w owning 32 cols (2 accs, 2 depth-2 B-streams, 1 shared a-read);
//     GEMM2 (4 waves x 16 cols); GEMM3 (2 waves); s = ||z3||^2 -> wsf.
//   bid 256..767 (P): 8 rows (half-wave = row): 12 float4/lane up-front,
//     butterfly-reduce d, n1, n2 -> wsf.
// wsf (f32): d@0, n1@4096, n2@8192, s@12288. wsb (ushort) at wsf+16384.
__global__ __launch_bounds__(256, 4) void pq_kernel(
    const float* __restrict__ X,
    const unsigned short* __restrict__ wsb,
    const float* __restrict__ b1,
    const float* __restrict__ b2,
    const float* __restrict__ b3,
    float* __restrict__ wsf)
{
    __shared__ __align__(16) char xq[16 * 1536];          // 16x768 bf16, XOR-swizzled
    __shared__ __align__(16) unsigned short z1[16][136];
    __shared__ __align__(16) unsigned short z2[16][72];
    __shared__ float sred[2][16];

    const int tid  = threadIdx.x;
    const int wid  = tid >> 6;     // 0..3
    const int lane = tid & 63;
    const int l15  = lane & 15;
    const int l4   = lane >> 4;

    if (blockIdx.x >= 256) {
        // ================= P path =================
        const int hl  = lane >> 5, ln = lane & 31;
        const int row = (int)(blockIdx.x - 256) * 8 + 2 * wid + hl;
        const float* base = X + (size_t)row * 2304;
        float4 p1[6], p2[6];
#pragma unroll
        for (int m = 0; m < 6; ++m) p1[m] = *(const float4*)(base + 768 + (ln + 32 * m) * 4);
#pragma unroll
        for (int m = 0; m < 6; ++m) p2[m] = *(const float4*)(base + 1536 + (ln + 32 * m) * 4);
        float dd = 0.f, aa = 0.f, bb = 0.f;
#pragma unroll
        for (int m = 0; m < 6; ++m) {
            float4 x = p1[m], y = p2[m];
            dd += x.x * y.x + x.y * y.y + x.z * y.z + x.w * y.w;
            aa += x.x * x.x + x.y * x.y + x.z * x.z + x.w * x.w;
            bb += y.x * y.x + y.y * y.y + y.z * y.z + y.w * y.w;
        }
#pragma unroll
        for (int m = 1; m < 32; m <<= 1) {
            dd += __shfl_xor(dd, m);
            aa += __shfl_xor(aa, m);
            bb += __shfl_xor(bb, m);
        }
        if (ln == 0) {
            wsf[row]        = dd;
            wsf[4096 + row] = aa;
            wsf[8192 + row] = bb;
        }
        return;
    }

    // ================= Q path =================
    const int row0 = (int)blockIdx.x * 16;
    const unsigned short* W1b = wsb;
    const unsigned short* W2b = wsb + 98304;
    const unsigned short* W3b = wsb + 106496;

    // ---- stage: 1536 16B-chunks / 256 thr = 6 each; all loads in flight ----
    {
        float4 v[12];
        int rr[6], cc6[6];
#pragma unroll
        for (int j = 0; j < 6; ++j) {
            int ci = tid + 256 * j;            // 0..1535
            int r  = ci / 96;
            int cc = ci - r * 96;
            rr[j] = r; cc6[j] = cc;
            const float* p = X + (size_t)(row0 + r) * 2304 + cc * 8;
            v[2 * j]     = *(const float4*)(p);
            v[2 * j + 1] = *(const float4*)(p + 4);
        }
#pragma unroll
        for (int j = 0; j < 6; ++j) {
            uint4 u;
            u.x = pack2(v[2 * j].x,     v[2 * j].y);
            u.y = pack2(v[2 * j].z,     v[2 * j].w);
            u.z = pack2(v[2 * j + 1].x, v[2 * j + 1].y);
            u.w = pack2(v[2 * j + 1].z, v[2 * j + 1].w);
            int byteoff = (rr[j] * 1536 + cc6[j] * 16) ^ ((rr[j] & 7) << 4);
            *(uint4*)(xq + byteoff) = u;
        }
    }
    __syncthreads();

    // ---- GEMM1: M=16, N=128, K=768; wave w owns cols 32w..32w+31 ----
    {
        f32x4 acc0 = {0.f, 0.f, 0.f, 0.f};
        f32x4 acc1 = {0.f, 0.f, 0.f, 0.f};
        const unsigned short* bp0 = W1b + (size_t)(32 * wid + l15) * 768 + l4 * 8;
        const unsigned short* bp1 = bp0 + 16 * 768;
        const int abase = l15 * 1536;
        const int aswz  = (l15 & 7) << 4;
        short8 b0c = *(const short8*)(bp0);
        short8 b1c = *(const short8*)(bp1);
#pragma unroll
        for (int k0 = 0; k0 < 768; k0 += 32) {
            short8 b0n = (k0 < 736) ? *(const short8*)(bp0 + k0 + 32) : b0c;
            short8 b1n = (k0 < 736) ? *(const short8*)(bp1 + k0 + 32) : b1c;
            short8 a = *(const short8*)(xq + ((abase + (k0 + l4 * 8) * 2) ^ aswz));
            acc0 = __builtin_amdgcn_mfma_f32_16x16x32_bf16(a, b0c, acc0, 0, 0, 0);
            acc1 = __builtin_amdgcn_mfma_f32_16x16x32_bf16(a, b1c, acc1, 0, 0, 0);
            b0c = b0n;
            b1c = b1n;
        }
        float bv0 = b1[32 * wid + l15];
        float bv1 = b1[32 * wid + 16 + l15];
#pragma unroll
        for (int r = 0; r < 4; ++r) {
            float v0 = fmaxf(acc0[r] + bv0, 0.f);
            float v1 = fmaxf(acc1[r] + bv1, 0.f);
            z1[4 * l4 + r][32 * wid + l15]      = (unsigned short)(bfhi(v0) >> 16);
            z1[4 * l4 + r][32 * wid + 16 + l15] = (unsigned short)(bfhi(v1) >> 16);
        }
    }
    __syncthreads();

    // ---- GEMM2: M=16, N=64, K=128; wave w owns cols 16w..16w+15 ----
    {
        f32x4 acc = {0.f, 0.f, 0.f, 0.f};
        const unsigned short* bp = W2b + (size_t)(16 * wid + l15) * 128 + l4 * 8;
#pragma unroll
        for (int ks = 0; ks < 4; ++ks) {
            short8 a = *(const short8*)&z1[l15][ks * 32 + l4 * 8];
            short8 b = *(const short8*)(bp + ks * 32);
            acc = __builtin_amdgcn_mfma_f32_16x16x32_bf16(a, b, acc, 0, 0, 0);
        }
        float bv = b2[16 * wid + l15];
#pragma unroll
        for (int r = 0; r < 4; ++r) {
            float v = fmaxf(acc[r] + bv, 0.f);
            z2[4 * l4 + r][16 * wid + l15] = (unsigned short)(bfhi(v) >> 16);
        }
    }
    __syncthreads();

    // ---- GEMM3: M=16, N=32, K=64 (waves 0-1); s = ||z3||^2 ----
    if (wid < 2) {
        f32x4 acc = {0.f, 0.f, 0.f, 0.f};
        const unsigned short* bp = W3b + (size_t)(16 * wid + l15) * 64 + l4 * 8;
#pragma unroll
        for (int ks = 0; ks < 2; ++ks) {
            short8 a = *(const short8*)&z2[l15][ks * 32 + l4 * 8];
            short8 b = *(const short8*)(bp + ks * 32);
            acc = __builtin_amdgcn_mfma_f32_16x16x32_bf16(a, b, acc, 0, 0, 0);
        }
        float bv = b3[16 * wid + l15];
        float sv[4];
#pragma unroll
        for (int r = 0; r < 4; ++r) {
            float v = fmaxf(acc[r] + bv, 0.f);
            sv[r] = v * v;
        }
#pragma unroll
        for (int m = 1; m < 16; m <<= 1)
#pragma unroll
            for (int r = 0; r < 4; ++r) sv[r] += __shfl_xor(sv[r], m);
        if (l15 == 0)
#pragma unroll
            for (int r = 0; r < 4; ++r) sred[wid][4 * l4 + r] = sv[r];
    }
    __syncthreads();
    if (tid < 16) wsf[12288 + row0 + tid] = sred[0][tid] + sred[1][tid];
}

// K2: combine. out = s*d / max(s*sqrt(n1*n2), eps)
__global__ __launch_bounds__(512) void combine(
    const float* __restrict__ wsf, float* __restrict__ out)
{
    int i = blockIdx.x * 512 + threadIdx.x;
    float d  = wsf[i];
    float n1 = wsf[4096 + i];
    float n2 = wsf[8192 + i];
    float s  = wsf[12288 + i];
    out[i] = (s * d) / fmaxf(s * sqrtf(n1 * n2), 1e-8f);
}

extern "C" void kernel_launch(void* const* d_in, const int* in_sizes, int n_in,
                              void* d_out, int out_size, void* d_ws, size_t ws_size,
                              hipStream_t stream)
{
    (void)in_sizes; (void)n_in; (void)out_size; (void)ws_size;
    const float* X  = (const float*)d_in[0];
    const float* W1 = (const float*)d_in[1];
    const float* b1 = (const float*)d_in[2];
    const float* W2 = (const float*)d_in[3];
    const float* b2 = (const float*)d_in[4];
    const float* W3 = (const float*)d_in[5];
    const float* b3 = (const float*)d_in[6];

    float* wsf          = (float*)d_ws;                   // d, n1, n2, s (4x4096)
    unsigned short* wsb = (unsigned short*)(wsf + 16384); // bf16 weights

    cvt_weights<<<dim3(106), dim3(256), 0, stream>>>(W1, W2, W3, wsb);
    pq_kernel<<<dim3(768), dim3(256), 0, stream>>>(X, wsb, b1, b2, b3, wsf);
    combine<<<dim3(8), dim3(512), 0, stream>>>(wsf, (float*)d_out);
}